// Round 1
// baseline (1301.584 us; speedup 1.0000x reference)
//
#include <hip/hip_runtime.h>

// CharBiLSTMEmbedder: N=32768 words, T=20 chars, E=50, H=50, V=200, out [N, 2H] fp32.
//
// Round-1 design (correctness-first, lane=word):
//  - k_G:   precompute G[dir][r][v] = emb'[v] . W_ih[r] + b_ih[r] + b_hh[r]
//           (emb row PAD=0 zeroed). Kills the x-part of the recurrence: 2x FLOP cut.
//  - k_W:   repack W_hh as [dir][j][k][m] so the per-j hot loop streams one
//           contiguous 800B row (wave-uniform -> scalar loads).
//  - k_lstm: 1024 blocks x 64 threads; each wave = 64 (word) lanes, one dir.
//           h held in registers (static index) for the FMAs; dynamic-index
//           h[j]/c[j] updates staged through a private LDS slice (no cross-lane
//           sharing -> no barriers in the step loop).

#define NW   32768
#define TT   20
#define EE   50
#define HH   50
#define VV   200
#define NG   200   // 4*H

__device__ __forceinline__ float frcp(float x) { return __builtin_amdgcn_rcpf(x); }
__device__ __forceinline__ float fsig(float x) { return frcp(1.0f + __expf(-x)); }
__device__ __forceinline__ float ftanhf(float x) { return 1.0f - 2.0f * frcp(1.0f + __expf(2.0f * x)); }

// G[d][r][v]: gate pre-activation contribution of char v for gate row r, dir d.
__global__ void k_G(const float* __restrict__ emb,
                    const float* __restrict__ Wih_f, const float* __restrict__ bih_f,
                    const float* __restrict__ bhh_f,
                    const float* __restrict__ Wih_b, const float* __restrict__ bih_b,
                    const float* __restrict__ bhh_b,
                    float* __restrict__ G) {
    int idx = blockIdx.x * 256 + threadIdx.x;
    if (idx >= 2 * NG * VV) return;
    int d = idx / (NG * VV);
    int r = (idx / VV) % NG;
    int v = idx % VV;
    const float* Wih = d ? Wih_b : Wih_f;
    const float* bih = d ? bih_b : bih_f;
    const float* bhh = d ? bhh_b : bhh_f;
    float s = bih[r] + bhh[r];
    if (v != 0) {  // PAD row of emb is zero
        #pragma unroll
        for (int e = 0; e < EE; ++e) s = fmaf(emb[v * EE + e], Wih[r * EE + e], s);
    }
    G[idx] = s;
}

// Wr[d][j][k][m] = W_hh_d[(k*50+j)][m]  (contiguous 4x50 row per unit j)
__global__ void k_W(const float* __restrict__ Whh_f, const float* __restrict__ Whh_b,
                    float* __restrict__ Wr) {
    int idx = blockIdx.x * 256 + threadIdx.x;
    if (idx >= 2 * NG * HH) return;
    int d = idx / (NG * HH);
    int rem = idx % (NG * HH);
    int j = rem / 200;
    int k = (rem / 50) % 4;
    int m = rem % 50;
    const float* Whh = d ? Whh_b : Whh_f;
    Wr[idx] = Whh[(k * HH + j) * HH + m];
}

__launch_bounds__(64)
__global__ void k_lstm(const int* __restrict__ chars, const int* __restrict__ lens,
                       const float* __restrict__ G, const float* __restrict__ Wr,
                       float* __restrict__ out) {
    int gb = blockIdx.x;          // 0..1023
    int d = gb >> 9;              // 512 blocks per direction
    int grp = gb & 511;
    int lane = threadIdx.x;       // 0..63
    int word = grp * 64 + lane;
    int L = lens[word];

    // wave-wide max length
    int mL = L;
    #pragma unroll
    for (int off = 32; off; off >>= 1) {
        int t = __shfl_xor(mL, off);
        mL = mL > t ? mL : t;
    }

    const float* Gd = G + d * (NG * VV);
    const float* Wd = Wr + d * (NG * HH);
    const int* crow = chars + word * TT;

    __shared__ float hb[64][52];
    __shared__ float cb[64][52];

    float hv[HH];
    #pragma unroll
    for (int m = 0; m < HH; ++m) {
        hv[m] = 0.0f;
        hb[lane][m] = 0.0f;
        cb[lane][m] = 0.0f;
    }

    for (int s = 0; s < mL; ++s) {
        bool valid = s < L;
        int p = d ? (L - 1 - s) : s;   // backward: chars L-1..0
        p = valid ? p : 0;
        int ch = crow[p];

        #pragma unroll 1
        for (int j = 0; j < HH; ++j) {
            const float* w = Wd + j * 200;   // [k][m], wave-uniform -> scalar loads
            float a0 = Gd[(j)        * VV + ch];
            float a1 = Gd[(j + 50)   * VV + ch];
            float a2 = Gd[(j + 100)  * VV + ch];
            float a3 = Gd[(j + 150)  * VV + ch];
            #pragma unroll
            for (int m = 0; m < HH; ++m) {
                float h = hv[m];
                a0 = fmaf(w[m],        h, a0);
                a1 = fmaf(w[50 + m],   h, a1);
                a2 = fmaf(w[100 + m],  h, a2);
                a3 = fmaf(w[150 + m],  h, a3);
            }
            float ig = fsig(a0);
            float fg = fsig(a1);
            float gg = ftanhf(a2);
            float og = fsig(a3);
            float cn = fg * cb[lane][j] + ig * gg;
            float hn = og * ftanhf(cn);
            if (valid) {
                cb[lane][j] = cn;
                hb[lane][j] = hn;
            }
        }
        // refresh register copy of h (same-thread LDS dependency, no barrier needed)
        #pragma unroll
        for (int m = 0; m < HH; ++m) hv[m] = hb[lane][m];
    }

    float* orow = out + word * (2 * HH) + d * HH;
    #pragma unroll
    for (int m = 0; m < HH; ++m) orow[m] = hv[m];
}

extern "C" void kernel_launch(void* const* d_in, const int* in_sizes, int n_in,
                              void* d_out, int out_size, void* d_ws, size_t ws_size,
                              hipStream_t stream) {
    const int*   chars = (const int*)d_in[0];
    const int*   lens  = (const int*)d_in[1];
    const float* emb   = (const float*)d_in[2];
    const float* Wih_f = (const float*)d_in[3];
    const float* Whh_f = (const float*)d_in[4];
    const float* bih_f = (const float*)d_in[5];
    const float* bhh_f = (const float*)d_in[6];
    const float* Wih_b = (const float*)d_in[7];
    const float* Whh_b = (const float*)d_in[8];
    const float* bih_b = (const float*)d_in[9];
    const float* bhh_b = (const float*)d_in[10];
    float* out = (float*)d_out;

    float* G  = (float*)d_ws;          // 2*200*200 = 80000 floats
    float* Wr = G + 2 * NG * VV;       // 2*200*50  = 20000 floats

    k_G<<<(2 * NG * VV + 255) / 256, 256, 0, stream>>>(emb, Wih_f, bih_f, bhh_f,
                                                       Wih_b, bih_b, bhh_b, G);
    k_W<<<(2 * NG * HH + 255) / 256, 256, 0, stream>>>(Whh_f, Whh_b, Wr);
    k_lstm<<<1024, 64, 0, stream>>>(chars, lens, G, Wr, out);
}

// Round 2
// 708.156 us; speedup vs baseline: 1.8380x; 1.8380x over previous
//
#include <hip/hip_runtime.h>

// CharBiLSTMEmbedder: N=32768 words, T=20, E=H=50, V=200, out [N,100] fp32.
//
// Round-2: split the 50-unit gate loop across 4 waves/block to get 4 waves/SIMD
// (round-1 had 1 wave/SIMD -> VALUBusy 33%).
//  - block = 256 thr = 4 waves; lane=word (64 words/block), wave w owns j-range.
//  - h shared via ping-pong LDS (1 barrier/step); c owner-private in LDS.
//  - invalid lanes copy h forward so ping-pong stays coherent past word end.
//  - G repacked [d][v][j][4]: one dwordx4 gather per j (was 4 scalar gathers).
//  - readfirstlane(wave-id, mL) so weight-row address is provably uniform -> s_load.

#define NW   32768
#define TT   20
#define EE   50
#define HH   50
#define VV   200
#define NG   200   // 4*H

__device__ __forceinline__ float frcp(float x) { return __builtin_amdgcn_rcpf(x); }
__device__ __forceinline__ float fsig(float x) { return frcp(1.0f + __expf(-x)); }
__device__ __forceinline__ float ftanhf(float x) { return 1.0f - 2.0f * frcp(1.0f + __expf(2.0f * x)); }

// Gt[d][v][j][k] = emb'[v] . W_ih[k*50+j] + b_ih[k*50+j] + b_hh[k*50+j]
__global__ void k_G(const float* __restrict__ emb,
                    const float* __restrict__ Wih_f, const float* __restrict__ bih_f,
                    const float* __restrict__ bhh_f,
                    const float* __restrict__ Wih_b, const float* __restrict__ bih_b,
                    const float* __restrict__ bhh_b,
                    float* __restrict__ G) {
    int idx = blockIdx.x * 256 + threadIdx.x;
    if (idx >= 2 * NG * VV) return;
    int d = idx / (NG * VV);
    int v = (idx / NG) % VV;
    int j = (idx % NG) / 4;
    int k = idx % 4;
    int r = k * HH + j;
    const float* Wih = d ? Wih_b : Wih_f;
    const float* bih = d ? bih_b : bih_f;
    const float* bhh = d ? bhh_b : bhh_f;
    float s = bih[r] + bhh[r];
    if (v != 0) {  // PAD row of emb is zero
        #pragma unroll
        for (int e = 0; e < EE; ++e) s = fmaf(emb[v * EE + e], Wih[r * EE + e], s);
    }
    G[idx] = s;
}

// Wr[d][j][k][m] = W_hh_d[(k*50+j)][m]  (contiguous 800B row per unit j)
__global__ void k_W(const float* __restrict__ Whh_f, const float* __restrict__ Whh_b,
                    float* __restrict__ Wr) {
    int idx = blockIdx.x * 256 + threadIdx.x;
    if (idx >= 2 * NG * HH) return;
    int d = idx / (NG * HH);
    int rem = idx % (NG * HH);
    int j = rem / 200;
    int k = (rem / 50) % 4;
    int m = rem % 50;
    const float* Whh = d ? Whh_b : Whh_f;
    Wr[idx] = Whh[(k * HH + j) * HH + m];
}

__launch_bounds__(256, 4)
__global__ void k_lstm(const int* __restrict__ chars, const int* __restrict__ lens,
                       const float* __restrict__ G, const float* __restrict__ Wr,
                       float* __restrict__ out) {
    int gb = blockIdx.x;               // 0..1023
    int d = gb >> 9;                   // 512 blocks per direction
    int grp = gb & 511;
    int tid = threadIdx.x;
    int lane = tid & 63;
    int word = grp * 64 + lane;
    int L = lens[word];

    // wave-id and j-range, forced wave-uniform so weight loads stay scalar
    int wv = __builtin_amdgcn_readfirstlane(tid >> 6);   // 0..3
    int jb = wv * 13;
    int jn = (jb + 13 <= HH) ? 13 : (HH - jb);           // 13,13,13,11

    // block-uniform max length (all 4 waves see the same 64 words)
    int mL = L;
    #pragma unroll
    for (int off = 32; off; off >>= 1) {
        int t = __shfl_xor(mL, off);
        mL = mL > t ? mL : t;
    }
    mL = __builtin_amdgcn_readfirstlane(mL);

    const float* Gd = G + d * (NG * VV);
    const float* Wd = Wr + d * (NG * HH);
    const int* crow = chars + word * TT;

    __shared__ float hb[2][64][52];   // ping-pong shared h
    __shared__ float cb[64][52];      // owner-private c

    // init own slice of buffer 0 and c
    for (int jj = 0; jj < jn; ++jj) {
        hb[0][lane][jb + jj] = 0.0f;
        cb[lane][jb + jj] = 0.0f;
    }

    float hv[52];

    for (int s = 0; s < mL; ++s) {
        __syncthreads();   // writes of step s-1 (and init) visible

        // full h into registers via bank-balanced float4 reads
        const float4* hr = (const float4*)&hb[s & 1][lane][0];
        #pragma unroll
        for (int q = 0; q < 13; ++q) {
            float4 t = hr[q];
            hv[4 * q + 0] = t.x; hv[4 * q + 1] = t.y;
            hv[4 * q + 2] = t.z; hv[4 * q + 3] = t.w;
        }

        bool valid = s < L;
        int p = valid ? (d ? (L - 1 - s) : s) : 0;
        int ch = crow[p];
        const float4* Grow = (const float4*)Gd + ch * HH;   // [j][4]
        float* hw = &hb[(s + 1) & 1][lane][0];
        float* cl = &cb[lane][0];

        #pragma unroll 1
        for (int jj = 0; jj < jn; ++jj) {
            int j = jb + jj;
            float4 g4 = Grow[j];
            const float* w = Wd + j * 200;   // wave-uniform -> s_load
            float a0 = g4.x, a1 = g4.y, a2 = g4.z, a3 = g4.w;
            #pragma unroll
            for (int m = 0; m < HH; ++m) {
                float h = hv[m];
                a0 = fmaf(w[m],       h, a0);
                a1 = fmaf(w[50 + m],  h, a1);
                a2 = fmaf(w[100 + m], h, a2);
                a3 = fmaf(w[150 + m], h, a3);
            }
            float ig = fsig(a0);
            float fg = fsig(a1);
            float gg = ftanhf(a2);
            float og = fsig(a3);
            float cold = cl[j];
            float cn = fg * cold + ig * gg;
            float hn = og * ftanhf(cn);
            cn = valid ? cn : cold;
            hn = valid ? hn : hv[j];   // carry h forward so ping-pong stays coherent
            cl[j] = cn;
            hw[j] = hn;
        }
    }

    // final h for own j-slice was written by this very thread -> no barrier
    const float* hf = &hb[mL & 1][lane][0];
    float* orow = out + word * (2 * HH) + d * HH;
    for (int jj = 0; jj < jn; ++jj) orow[jb + jj] = hf[jb + jj];
}

extern "C" void kernel_launch(void* const* d_in, const int* in_sizes, int n_in,
                              void* d_out, int out_size, void* d_ws, size_t ws_size,
                              hipStream_t stream) {
    const int*   chars = (const int*)d_in[0];
    const int*   lens  = (const int*)d_in[1];
    const float* emb   = (const float*)d_in[2];
    const float* Wih_f = (const float*)d_in[3];
    const float* Whh_f = (const float*)d_in[4];
    const float* bih_f = (const float*)d_in[5];
    const float* bhh_f = (const float*)d_in[6];
    const float* Wih_b = (const float*)d_in[7];
    const float* Whh_b = (const float*)d_in[8];
    const float* bih_b = (const float*)d_in[9];
    const float* bhh_b = (const float*)d_in[10];
    float* out = (float*)d_out;

    float* G  = (float*)d_ws;          // 2*200*200 = 80000 floats
    float* Wr = G + 2 * NG * VV;       // 2*200*50  = 20000 floats

    k_G<<<(2 * NG * VV + 255) / 256, 256, 0, stream>>>(emb, Wih_f, bih_f, bhh_f,
                                                       Wih_b, bih_b, bhh_b, G);
    k_W<<<(2 * NG * HH + 255) / 256, 256, 0, stream>>>(Whh_f, Whh_b, Wr);
    k_lstm<<<1024, 256, 0, stream>>>(chars, lens, G, Wr, out);
}

// Round 3
// 584.752 us; speedup vs baseline: 2.2259x; 1.2110x over previous
//
#include <hip/hip_runtime.h>

// CharBiLSTMEmbedder: N=32768 words, T=20, E=H=50, V=200, out [N,100] fp32.
//
// Round-3: fix round-2's scratch disaster + LDS bank conflicts.
//  - hv[j] dynamic index (invalid-lane h carry) replaced by an LDS read ->
//    hv[] is statically indexed only -> lives in VGPRs (round-2: 1.03 GB of
//    scratch writes, VGPR_Count=52 proved it was demoted to scratch).
//  - LDS state transposed to [j][lane]: writes lane-contiguous (conflict-free),
//    reads at fixed lane are 2-lanes/bank (free). Round-2 stride-52 rows had
//    gcd(52,32)=4 -> 8-way conflicts (1.9e7 SQ_LDS_BANK_CONFLICT).
//  - Structure unchanged: 1024 blocks x 4 waves, lane=word, wave w owns
//    j-range, h ping-pong with 1 barrier/step, c owner-private.

#define NW   32768
#define TT   20
#define EE   50
#define HH   50
#define VV   200
#define NG   200   // 4*H

__device__ __forceinline__ float frcp(float x) { return __builtin_amdgcn_rcpf(x); }
__device__ __forceinline__ float fsig(float x) { return frcp(1.0f + __expf(-x)); }
__device__ __forceinline__ float ftanhf(float x) { return 1.0f - 2.0f * frcp(1.0f + __expf(2.0f * x)); }

// G[d][v][j][k] = emb'[v] . W_ih[k*50+j] + b_ih[k*50+j] + b_hh[k*50+j]
__global__ void k_G(const float* __restrict__ emb,
                    const float* __restrict__ Wih_f, const float* __restrict__ bih_f,
                    const float* __restrict__ bhh_f,
                    const float* __restrict__ Wih_b, const float* __restrict__ bih_b,
                    const float* __restrict__ bhh_b,
                    float* __restrict__ G) {
    int idx = blockIdx.x * 256 + threadIdx.x;
    if (idx >= 2 * NG * VV) return;
    int d = idx / (NG * VV);
    int v = (idx / NG) % VV;
    int j = (idx % NG) / 4;
    int k = idx % 4;
    int r = k * HH + j;
    const float* Wih = d ? Wih_b : Wih_f;
    const float* bih = d ? bih_b : bih_f;
    const float* bhh = d ? bhh_b : bhh_f;
    float s = bih[r] + bhh[r];
    if (v != 0) {  // PAD row of emb is zero
        #pragma unroll
        for (int e = 0; e < EE; ++e) s = fmaf(emb[v * EE + e], Wih[r * EE + e], s);
    }
    G[idx] = s;
}

// Wr[d][j][k][m] = W_hh_d[(k*50+j)][m]  (contiguous 800B row per unit j)
__global__ void k_W(const float* __restrict__ Whh_f, const float* __restrict__ Whh_b,
                    float* __restrict__ Wr) {
    int idx = blockIdx.x * 256 + threadIdx.x;
    if (idx >= 2 * NG * HH) return;
    int d = idx / (NG * HH);
    int rem = idx % (NG * HH);
    int j = rem / 200;
    int k = (rem / 50) % 4;
    int m = rem % 50;
    const float* Whh = d ? Whh_b : Whh_f;
    Wr[idx] = Whh[(k * HH + j) * HH + m];
}

__launch_bounds__(256, 4)
__global__ void k_lstm(const int* __restrict__ chars, const int* __restrict__ lens,
                       const float* __restrict__ G, const float* __restrict__ Wr,
                       float* __restrict__ out) {
    int gb = blockIdx.x;               // 0..1023
    int d = gb >> 9;                   // 512 blocks per direction
    int grp = gb & 511;
    int tid = threadIdx.x;
    int lane = tid & 63;
    int word = grp * 64 + lane;
    int L = lens[word];

    // wave-id and j-range, forced wave-uniform so weight loads stay scalar
    int wv = __builtin_amdgcn_readfirstlane(tid >> 6);   // 0..3
    int jb = wv * 13;
    int jn = (jb + 13 <= HH) ? 13 : (HH - jb);           // 13,13,13,11

    // block-uniform max length (all 4 waves see the same 64 words)
    int mL = L;
    #pragma unroll
    for (int off = 32; off; off >>= 1) {
        int t = __shfl_xor(mL, off);
        mL = mL > t ? mL : t;
    }
    mL = __builtin_amdgcn_readfirstlane(mL);

    const float* Gd = G + d * (NG * VV);
    const float* Wd = Wr + d * (NG * HH);
    const int* crow = chars + word * TT;

    // [j][lane] layout: writes lane-contiguous (conflict-free),
    // per-lane reads 2-way (free).
    __shared__ float hb[2][HH][64];   // ping-pong shared h
    __shared__ float cb[HH][64];      // owner-private c

    for (int jj = 0; jj < jn; ++jj) {
        hb[0][jb + jj][lane] = 0.0f;
        cb[jb + jj][lane] = 0.0f;
    }

    float hv[HH];   // statically indexed ONLY -> stays in VGPRs

    for (int s = 0; s < mL; ++s) {
        __syncthreads();   // writes of step s-1 (and init) visible

        const float* hbR = &hb[s & 1][0][0];
        float* hbW = &hb[(s + 1) & 1][0][0];

        #pragma unroll
        for (int m = 0; m < HH; ++m) hv[m] = hbR[m * 64 + lane];

        bool valid = s < L;
        int p = valid ? (d ? (L - 1 - s) : s) : 0;
        int ch = crow[p];
        const float4* Grow = (const float4*)Gd + ch * HH;   // [j][4]

        #pragma unroll 1
        for (int jj = 0; jj < jn; ++jj) {
            int j = jb + jj;
            float4 g4 = Grow[j];
            const float* w = Wd + j * 200;   // wave-uniform -> s_load
            float a0 = g4.x, a1 = g4.y, a2 = g4.z, a3 = g4.w;
            #pragma unroll
            for (int m = 0; m < HH; ++m) {
                float h = hv[m];
                a0 = fmaf(w[m],       h, a0);
                a1 = fmaf(w[50 + m],  h, a1);
                a2 = fmaf(w[100 + m], h, a2);
                a3 = fmaf(w[150 + m], h, a3);
            }
            float ig = fsig(a0);
            float fg = fsig(a1);
            float gg = ftanhf(a2);
            float og = fsig(a3);
            float cold = cb[j][lane];
            float hold = hbR[j * 64 + lane];   // LDS read, NOT hv[j] (keeps hv in regs)
            float cn = fg * cold + ig * gg;
            float hn = og * ftanhf(cn);
            cb[j][lane] = valid ? cn : cold;
            hbW[j * 64 + lane] = valid ? hn : hold;
        }
    }

    // final h for own j-slice was written by this very thread -> no barrier
    const float* hf = &hb[mL & 1][0][0];
    float* orow = out + word * (2 * HH) + d * HH;
    for (int jj = 0; jj < jn; ++jj) orow[jb + jj] = hf[(jb + jj) * 64 + lane];
}

extern "C" void kernel_launch(void* const* d_in, const int* in_sizes, int n_in,
                              void* d_out, int out_size, void* d_ws, size_t ws_size,
                              hipStream_t stream) {
    const int*   chars = (const int*)d_in[0];
    const int*   lens  = (const int*)d_in[1];
    const float* emb   = (const float*)d_in[2];
    const float* Wih_f = (const float*)d_in[3];
    const float* Whh_f = (const float*)d_in[4];
    const float* bih_f = (const float*)d_in[5];
    const float* bhh_f = (const float*)d_in[6];
    const float* Wih_b = (const float*)d_in[7];
    const float* Whh_b = (const float*)d_in[8];
    const float* bih_b = (const float*)d_in[9];
    const float* bhh_b = (const float*)d_in[10];
    float* out = (float*)d_out;

    float* G  = (float*)d_ws;          // 2*200*200 = 80000 floats
    float* Wr = G + 2 * NG * VV;       // 2*200*50  = 20000 floats

    k_G<<<(2 * NG * VV + 255) / 256, 256, 0, stream>>>(emb, Wih_f, bih_f, bhh_f,
                                                       Wih_b, bih_b, bhh_b, G);
    k_W<<<(2 * NG * HH + 255) / 256, 256, 0, stream>>>(Whh_f, Whh_b, Wr);
    k_lstm<<<1024, 256, 0, stream>>>(chars, lens, G, Wr, out);
}

// Round 4
// 516.204 us; speedup vs baseline: 2.5215x; 1.1328x over previous
//
#include <hip/hip_runtime.h>

// CharBiLSTMEmbedder: N=32768 words, T=20, E=H=50, V=200, out [N,100] fp32.
//
// Round-4: move the recurrent matmul to MFMA (bf16 in, fp32 acc).
//   per step:  gates[200 x 16words] = Whh_bf16[200x50pad64] . h_bf16[50pad64 x 16]
//   - wave owns 16 words for one dir; rows ordered R=4u+g so C/D lane
//     (quad,reg,n) = (unit 4t+quad, gate reg, word n): all 4 gates of one unit
//     in one lane -> elementwise fully lane-local, c-state in 13 VGPRs.
//   - acc init = G[char][u][0..3] gather (fp32) -> no separate bias/x add.
//   - h goes C-layout -> per-wave LDS (bf16, XOR-swizzled) -> B-frags.
//     Same-wave ordering => NO barriers in the step loop.
//   - A (Whh) staged once per block into LDS, same swizzle; ds_read_b128
//     A/B reads are conflict-optimal (8 phases).
// Precision: W,h quantized bf16 (c, gates, G stay fp32): ~3e-3 abs err vs
// 8.67e-3 threshold.

#define TT    20
#define HH    50
#define VV    200
#define TILES 13   // 13*16 = 208 rows >= 200

typedef __attribute__((ext_vector_type(8))) short bf16x8;
typedef __attribute__((ext_vector_type(4))) float f32x4;

__device__ __forceinline__ float frcp(float x) { return __builtin_amdgcn_rcpf(x); }
__device__ __forceinline__ float fsig(float x) { return frcp(1.0f + __expf(-x)); }
__device__ __forceinline__ float ftanhf(float x) { return 1.0f - 2.0f * frcp(1.0f + __expf(2.0f * x)); }

__device__ __forceinline__ short f2bf(float x) {  // RNE fp32 -> bf16
    unsigned b = __builtin_bit_cast(unsigned, x);
    unsigned r = (b + 0x7FFFu + ((b >> 16) & 1u)) >> 16;
    return (short)r;
}

// G[d][v][u][g] = emb'[v] . W_ih[g*50+u] + b_ih[g*50+u] + b_hh[g*50+u]
// u padded to 52 (u>=50 rows are zero).
__global__ void k_G(const float* __restrict__ emb,
                    const float* __restrict__ Wih_f, const float* __restrict__ bih_f,
                    const float* __restrict__ bhh_f,
                    const float* __restrict__ Wih_b, const float* __restrict__ bih_b,
                    const float* __restrict__ bhh_b,
                    float* __restrict__ G) {
    int idx = blockIdx.x * 256 + threadIdx.x;
    if (idx >= 2 * VV * 52 * 4) return;
    int d = idx / (VV * 52 * 4);
    int rem = idx % (VV * 52 * 4);
    int v = rem / (52 * 4);
    int u = (rem >> 2) % 52;
    int g = idx & 3;
    if (u >= HH) { G[idx] = 0.0f; return; }
    int r = g * HH + u;
    const float* Wih = d ? Wih_b : Wih_f;
    const float* bih = d ? bih_b : bih_f;
    const float* bhh = d ? bhh_b : bhh_f;
    float s = bih[r] + bhh[r];
    if (v != 0) {  // PAD row of emb is zero
        #pragma unroll
        for (int e = 0; e < HH; ++e) s = fmaf(emb[v * HH + e], Wih[r * HH + e], s);
    }
    G[idx] = s;
}

__launch_bounds__(256, 3)
__global__ void k_lstm(const int* __restrict__ chars, const int* __restrict__ lens,
                       const float* __restrict__ G,
                       const float* __restrict__ Whh_f, const float* __restrict__ Whh_b,
                       float* __restrict__ out) {
    __shared__ __align__(16) short Wa[TILES * 16 * 64];  // [t][m][k ^ swizzle(m)]
    __shared__ __align__(16) short hs[4][16 * 64];       // per-wave: [word n][unit ^ swizzle(n)]

    int gb   = blockIdx.x;
    int d    = gb >> 9;            // 512 blocks per direction
    int grp  = gb & 511;
    int tid  = threadIdx.x;
    int lane = tid & 63;
    int wv   = __builtin_amdgcn_readfirstlane(tid >> 6);
    int quad = lane >> 4;
    int n    = lane & 15;          // word-within-wave; also A-row m (both = lane&15)
    int x7   = n & 7;

    const float* Whh = d ? Whh_b : Whh_f;

    // ---- stage Whh -> Wa (bf16, row R=16t+m -> gate m&3, unit 4t+(m>>2)) ----
    for (int e = tid; e < TILES * 16 * 64; e += 256) {
        int t = e >> 10, m = (e >> 6) & 15, k = e & 63;
        int u = 4 * t + (m >> 2), g = m & 3;
        float val = (k < HH && u < HH) ? Whh[(g * HH + u) * HH + k] : 0.0f;
        int ksw = (k & 7) | (((k >> 3) ^ (m & 7)) << 3);
        Wa[(e & ~63) + ksw] = f2bf(val);
    }
    // ---- zero own h buffer (h_init = 0, and k-pad rows stay 0 forever) ----
    {
        int4 z = {0, 0, 0, 0};
        int4* hz = (int4*)hs[wv];
        hz[lane * 2 + 0] = z;
        hz[lane * 2 + 1] = z;
    }
    __syncthreads();

    int word = (grp * 4 + wv) * 16 + n;
    int L = lens[word];
    int mL = L;                    // max over the wave's 16 words
    #pragma unroll
    for (int off = 8; off; off >>= 1) {
        int t2 = __shfl_xor(mL, off);
        mL = mL > t2 ? mL : t2;
    }
    mL = __builtin_amdgcn_readfirstlane(mL);

    const int* crow = chars + word * TT;
    const f32x4* G4 = (const f32x4*)G + (size_t)d * VV * 52;
    const bf16x8* ap = (const bf16x8*)Wa;
    const bf16x8* bp = (const bf16x8*)hs[wv];
    short* hw = hs[wv];

    int pa0 = quad ^ x7;           // swizzled k-group, k-step 0 (k 0..31)
    int pa1 = (quad + 4) ^ x7;     // k-step 1 (k 32..63)

    float cst[TILES], hf[TILES];
    #pragma unroll
    for (int t = 0; t < TILES; ++t) { cst[t] = 0.0f; hf[t] = 0.0f; }

    #pragma unroll 1
    for (int s = 0; s < mL; ++s) {
        bool valid = s < L;
        int p = valid ? (d ? (L - 1 - s) : s) : 0;
        int v = crow[p];
        const f32x4* Gv = G4 + v * 52;

        bf16x8 B0 = bp[n * 8 + pa0];     // h of step s-1, B-operand layout
        bf16x8 B1 = bp[n * 8 + pa1];

        // pass 1: all MFMAs (accs stay live; tiles independent -> pipelined)
        f32x4 acc[TILES];
        #pragma unroll
        for (int t = 0; t < TILES; ++t) {
            int u = 4 * t + quad;
            f32x4 a = Gv[u];             // acc init = char preactivation (fp32)
            bf16x8 A0 = ap[(t * 16 + n) * 8 + pa0];
            bf16x8 A1 = ap[(t * 16 + n) * 8 + pa1];
            a = __builtin_amdgcn_mfma_f32_16x16x32_bf16(A0, B0, a, 0, 0, 0);
            a = __builtin_amdgcn_mfma_f32_16x16x32_bf16(A1, B1, a, 0, 0, 0);
            acc[t] = a;
        }
        // pass 2: lane-local gate math; h back to LDS in bf16
        #pragma unroll
        for (int t = 0; t < TILES; ++t) {
            int u = 4 * t + quad;
            float ig = fsig(acc[t][0]);
            float fg = fsig(acc[t][1]);
            float gg = ftanhf(acc[t][2]);
            float og = fsig(acc[t][3]);
            float cold = cst[t];
            float cn = fg * cold + ig * gg;
            float hn = og * ftanhf(cn);
            bool upd = valid && (u < HH);
            cst[t] = upd ? cn : cold;
            hf[t]  = upd ? hn : hf[t];
            if (upd) {
                int idx = n * 64 + (((u >> 3) ^ x7) << 3) + (u & 7);
                hw[idx] = f2bf(hn);      // skipped when invalid -> h frozen
            }
        }
    }

    float* orow = out + (size_t)word * (2 * HH) + d * HH;
    #pragma unroll
    for (int t = 0; t < TILES; ++t) {
        int u = 4 * t + quad;
        if (u < HH) orow[u] = hf[t];     // fp32 h (not bf16-rounded)
    }
}

extern "C" void kernel_launch(void* const* d_in, const int* in_sizes, int n_in,
                              void* d_out, int out_size, void* d_ws, size_t ws_size,
                              hipStream_t stream) {
    const int*   chars = (const int*)d_in[0];
    const int*   lens  = (const int*)d_in[1];
    const float* emb   = (const float*)d_in[2];
    const float* Wih_f = (const float*)d_in[3];
    const float* Whh_f = (const float*)d_in[4];
    const float* bih_f = (const float*)d_in[5];
    const float* bhh_f = (const float*)d_in[6];
    const float* Wih_b = (const float*)d_in[7];
    const float* Whh_b = (const float*)d_in[8];
    const float* bih_b = (const float*)d_in[9];
    const float* bhh_b = (const float*)d_in[10];
    float* out = (float*)d_out;

    float* G = (float*)d_ws;   // 2*200*52*4 = 83200 floats = 332.8 KB

    k_G<<<(2 * VV * 52 * 4 + 255) / 256, 256, 0, stream>>>(emb, Wih_f, bih_f, bhh_f,
                                                           Wih_b, bih_b, bhh_b, G);
    k_lstm<<<1024, 256, 0, stream>>>(chars, lens, G, Whh_f, Whh_b, out);
}

// Round 5
// 191.998 us; speedup vs baseline: 6.7792x; 2.6886x over previous
//
#include <hip/hip_runtime.h>

// CharBiLSTMEmbedder: N=32768 words, T=20, E=H=50, V=200, out [N,100] fp32.
//
// Round-5: evict ALL global memory from the step loop (R4 was HBM-latency
// bound: 531 MB FETCH from per-step G gathers).
//  - G staged in LDS as bf16 [v][u][4g], row stride 53*8B (bank-rotating);
//    k_G writes the exact image; k_lstm block-copies 84.8 KB coalesced.
//  - Whh A-operand image (bf16, MFMA-swizzled) precomputed by k_W in ws;
//    block-copied 26.6 KB.
//  - chars staged as u8 in LDS (V=200<256): no global loads per step.
//  - 512-thr blocks (8 waves = 2/SIMD; <=256 regs -> no spill risk),
//    LDS 130 KB -> 1 block/CU, 512 blocks, one dir per block.
//  - Step loop: LDS + MFMA + VALU only, no barriers (per-wave h buffers).

#define TT    20
#define HH    50
#define VV    200
#define TILES 13        // 13*16 = 208 rows >= 200
#define GSTR  212       // G LDS row stride in shorts (53 units * 4 gates)
#define GSH   (VV * GSTR)        // 42400 shorts per dir
#define WSH   (TILES * 16 * 64)  // 13312 shorts per dir

typedef __attribute__((ext_vector_type(8))) short bf16x8;
typedef __attribute__((ext_vector_type(4))) short s16x4;
typedef __attribute__((ext_vector_type(4))) float f32x4;

__device__ __forceinline__ float frcp(float x) { return __builtin_amdgcn_rcpf(x); }
__device__ __forceinline__ float fsig(float x) { return frcp(1.0f + __expf(-x)); }
__device__ __forceinline__ float ftanhf(float x) { return 1.0f - 2.0f * frcp(1.0f + __expf(2.0f * x)); }

__device__ __forceinline__ short f2bf(float x) {  // RNE fp32 -> bf16
    unsigned b = __builtin_bit_cast(unsigned, x);
    unsigned r = (b + 0x7FFFu + ((b >> 16) & 1u)) >> 16;
    return (short)r;
}
__device__ __forceinline__ float bf2f(short s) {
    return __builtin_bit_cast(float, ((unsigned)(unsigned short)s) << 16);
}

// Gimg[d][v*GSTR + u*4 + g] = bf16( emb'[v].W_ih[g*50+u] + b_ih[] + b_hh[] )
__global__ void k_G(const float* __restrict__ emb,
                    const float* __restrict__ Wih_f, const float* __restrict__ bih_f,
                    const float* __restrict__ bhh_f,
                    const float* __restrict__ Wih_b, const float* __restrict__ bih_b,
                    const float* __restrict__ bhh_b,
                    short* __restrict__ Gimg) {
    int idx = blockIdx.x * 256 + threadIdx.x;
    if (idx >= 2 * GSH) return;
    int d = idx / GSH;
    int rem = idx % GSH;
    int v = rem / GSTR;
    int u = (rem % GSTR) >> 2;
    int g = idx & 3;
    if (u >= HH) { Gimg[idx] = 0; return; }
    int r = g * HH + u;
    const float* Wih = d ? Wih_b : Wih_f;
    const float* bih = d ? bih_b : bih_f;
    const float* bhh = d ? bhh_b : bhh_f;
    float s = bih[r] + bhh[r];
    if (v != 0) {  // PAD row of emb is zero
        #pragma unroll
        for (int e = 0; e < HH; ++e) s = fmaf(emb[v * HH + e], Wih[r * HH + e], s);
    }
    Gimg[idx] = f2bf(s);
}

// Wimg[d][...] : MFMA A-operand image of Whh, rows R=16t+m -> (u=4t+(m>>2), g=m&3),
// k swizzled: ksw = (k&7) | (((k>>3)^(m&7))<<3)
__global__ void k_W(const float* __restrict__ Whh_f, const float* __restrict__ Whh_b,
                    short* __restrict__ Wimg) {
    int idx = blockIdx.x * 256 + threadIdx.x;
    if (idx >= 2 * WSH) return;
    int d = idx / WSH;
    int e = idx % WSH;
    int t = e >> 10, m = (e >> 6) & 15, k = e & 63;
    int u = 4 * t + (m >> 2), g = m & 3;
    const float* Whh = d ? Whh_b : Whh_f;
    float val = (k < HH && u < HH) ? Whh[(g * HH + u) * HH + k] : 0.0f;
    int ksw = (k & 7) | (((k >> 3) ^ (m & 7)) << 3);
    Wimg[d * WSH + (e & ~63) + ksw] = f2bf(val);
}

__launch_bounds__(512, 1)
__global__ void k_lstm(const int* __restrict__ chars, const int* __restrict__ lens,
                       const short* __restrict__ Gimg, const short* __restrict__ Wimg,
                       float* __restrict__ out) {
    __shared__ __align__(16) short Wa[WSH];        // 26624 B
    __shared__ __align__(16) short Gl[GSH];        // 84800 B
    __shared__ __align__(16) short hs[8][1024];    // 16384 B per-wave h (bf16, swizzled)
    __shared__ unsigned char cs[8][320];           // 2560 B per-wave chars (u8)

    int gb   = blockIdx.x;         // 0..511
    int d    = gb >> 8;            // 256 blocks per direction
    int grp  = gb & 255;
    int tid  = threadIdx.x;        // 0..511
    int lane = tid & 63;
    int wv   = __builtin_amdgcn_readfirstlane(tid >> 6);   // 0..7
    int quad = lane >> 4;
    int n    = lane & 15;
    int x7   = n & 7;

    // ---- stage: coalesced block copies ----
    {
        const int4* src = (const int4*)(Wimg + d * WSH);   // 1664 int4
        int4* dst = (int4*)Wa;
        for (int i = tid; i < WSH / 8; i += 512) dst[i] = src[i];
    }
    {
        const int4* src = (const int4*)(Gimg + d * GSH);   // 5300 int4
        int4* dst = (int4*)Gl;
        for (int i = tid; i < GSH / 8; i += 512) dst[i] = src[i];
    }
    {
        int4 z = {0, 0, 0, 0};
        int4* hz = (int4*)&hs[0][0];
        for (int i = tid; i < 8 * 1024 / 8; i += 512) hz[i] = z;
    }
    {   // wave's 16 words x 20 chars, coalesced int loads -> u8 LDS
        int wbase = (grp * 8 + wv) * 16;                   // first word of wave
        for (int i = lane; i < 16 * TT; i += 64)
            cs[wv][i] = (unsigned char)chars[wbase * TT + i];
    }
    __syncthreads();

    int word = (grp * 8 + wv) * 16 + n;
    int L = lens[word];
    int mL = L;
    #pragma unroll
    for (int off = 8; off; off >>= 1) {
        int t2 = __shfl_xor(mL, off);
        mL = mL > t2 ? mL : t2;
    }
    mL = __builtin_amdgcn_readfirstlane(mL);

    const bf16x8* ap = (const bf16x8*)Wa;
    const bf16x8* bp = (const bf16x8*)hs[wv];
    short* hw = hs[wv];
    const unsigned char* cw = cs[wv] + n * TT;

    int pa0 = quad ^ x7;           // swizzled k-group, k 0..31
    int pa1 = (quad + 4) ^ x7;     // k 32..63

    float cst[TILES], hf[TILES];
    #pragma unroll
    for (int t = 0; t < TILES; ++t) { cst[t] = 0.0f; hf[t] = 0.0f; }

    #pragma unroll 1
    for (int s = 0; s < mL; ++s) {
        bool valid = s < L;
        int p = valid ? (d ? (L - 1 - s) : s) : 0;
        int v = cw[p];

        bf16x8 B0 = bp[n * 8 + pa0];     // h of step s-1, B-operand layout
        bf16x8 B1 = bp[n * 8 + pa1];

        // pass 1: MFMAs; acc init = bf16 G from LDS (char preactivation)
        f32x4 acc[TILES];
        #pragma unroll
        for (int t = 0; t < TILES; ++t) {
            int u = 4 * t + quad;
            s16x4 gv = *(const s16x4*)&Gl[v * GSTR + u * 4];
            f32x4 a;
            a[0] = bf2f(gv[0]); a[1] = bf2f(gv[1]);
            a[2] = bf2f(gv[2]); a[3] = bf2f(gv[3]);
            bf16x8 A0 = ap[(t * 16 + n) * 8 + pa0];
            bf16x8 A1 = ap[(t * 16 + n) * 8 + pa1];
            a = __builtin_amdgcn_mfma_f32_16x16x32_bf16(A0, B0, a, 0, 0, 0);
            a = __builtin_amdgcn_mfma_f32_16x16x32_bf16(A1, B1, a, 0, 0, 0);
            acc[t] = a;
        }
        // pass 2: lane-local gate math; h back to LDS in bf16
        #pragma unroll
        for (int t = 0; t < TILES; ++t) {
            int u = 4 * t + quad;
            float ig = fsig(acc[t][0]);
            float fg = fsig(acc[t][1]);
            float gg = ftanhf(acc[t][2]);
            float og = fsig(acc[t][3]);
            float cold = cst[t];
            float cn = fg * cold + ig * gg;
            float hn = og * ftanhf(cn);
            bool upd = valid && (u < HH);
            cst[t] = upd ? cn : cold;
            hf[t]  = upd ? hn : hf[t];
            if (upd) {
                int idx = n * 64 + (((u >> 3) ^ x7) << 3) + (u & 7);
                hw[idx] = f2bf(hn);      // skipped when invalid -> h frozen
            }
        }
    }

    float* orow = out + (size_t)word * (2 * HH) + d * HH;
    #pragma unroll
    for (int t = 0; t < TILES; ++t) {
        int u = 4 * t + quad;
        if (u < HH) orow[u] = hf[t];     // fp32 h
    }
}

extern "C" void kernel_launch(void* const* d_in, const int* in_sizes, int n_in,
                              void* d_out, int out_size, void* d_ws, size_t ws_size,
                              hipStream_t stream) {
    const int*   chars = (const int*)d_in[0];
    const int*   lens  = (const int*)d_in[1];
    const float* emb   = (const float*)d_in[2];
    const float* Wih_f = (const float*)d_in[3];
    const float* Whh_f = (const float*)d_in[4];
    const float* bih_f = (const float*)d_in[5];
    const float* bhh_f = (const float*)d_in[6];
    const float* Wih_b = (const float*)d_in[7];
    const float* Whh_b = (const float*)d_in[8];
    const float* bih_b = (const float*)d_in[9];
    const float* bhh_b = (const float*)d_in[10];
    float* out = (float*)d_out;

    short* Gimg = (short*)d_ws;          // 2*42400 shorts = 169600 B
    short* Wimg = Gimg + 2 * GSH;        // 2*13312 shorts =  53248 B

    k_G<<<(2 * GSH + 255) / 256, 256, 0, stream>>>(emb, Wih_f, bih_f, bhh_f,
                                                   Wih_b, bih_b, bhh_b, Gimg);
    k_W<<<(2 * WSH + 255) / 256, 256, 0, stream>>>(Whh_f, Whh_b, Wimg);
    k_lstm<<<512, 512, 0, stream>>>(chars, lens, Gimg, Wimg, out);
}

// Round 6
// 159.623 us; speedup vs baseline: 8.1541x; 1.2028x over previous
//
#include <hip/hip_runtime.h>

// CharBiLSTMEmbedder: N=32768 words, T=20, E=H=50, V=200, out [N,100] fp32.
//
// Round-6: counting-sort words by length (21 buckets, descending) so each
// wave's 16 words have ~equal length: wave-steps 4096*18.9 -> 4096*10.2
// (unsorted waves pay max of 16 random lengths; sorted pay the mean).
// Descending order => LPT block schedule on 256 CUs.
//  - k_prep: one kernel = G image + Whh A-image + per-block length histogram.
//  - k_scan/k_scat: counting-sort perm (bucket-major, L=20 first).
//  - k_lstm: unchanged step loop (LDS-only, MFMA, no barriers), word=perm[slot].

#define TT    20
#define HH    50
#define VV    200
#define TILES 13        // 13*16 = 208 rows >= 200
#define GSTR  212       // G LDS row stride in shorts (53 units * 4 gates)
#define GSH   (VV * GSTR)        // 42400 shorts per dir
#define WSH   (TILES * 16 * 64)  // 13312 shorts per dir
#define NW    32768
#define NB_G  332       // ceil(2*GSH/256)
#define NB_W  104       // ceil(2*WSH/256)
#define NB_H  128       // 128*256 = 32768 words

typedef __attribute__((ext_vector_type(8))) short bf16x8;
typedef __attribute__((ext_vector_type(4))) short s16x4;
typedef __attribute__((ext_vector_type(4))) float f32x4;

__device__ __forceinline__ float frcp(float x) { return __builtin_amdgcn_rcpf(x); }
__device__ __forceinline__ float fsig(float x) { return frcp(1.0f + __expf(-x)); }
__device__ __forceinline__ float ftanhf(float x) { return 1.0f - 2.0f * frcp(1.0f + __expf(2.0f * x)); }

__device__ __forceinline__ short f2bf(float x) {  // RNE fp32 -> bf16
    unsigned b = __builtin_bit_cast(unsigned, x);
    unsigned r = (b + 0x7FFFu + ((b >> 16) & 1u)) >> 16;
    return (short)r;
}
__device__ __forceinline__ float bf2f(short s) {
    return __builtin_bit_cast(float, ((unsigned)(unsigned short)s) << 16);
}

// One kernel, three jobs by block range:
//  [0,NB_G): Gimg[d][v*GSTR+u*4+g] = bf16(emb'[v].W_ih[g*50+u] + b_ih + b_hh)
//  [NB_G,NB_G+NB_W): Wimg = MFMA A-operand image of Whh (bf16, k-swizzled)
//  [NB_G+NB_W, +NB_H): cnt[block][21] = length histogram of 256 words
__global__ void k_prep(const float* __restrict__ emb,
                       const float* __restrict__ Wih_f, const float* __restrict__ bih_f,
                       const float* __restrict__ bhh_f,
                       const float* __restrict__ Wih_b, const float* __restrict__ bih_b,
                       const float* __restrict__ bhh_b,
                       const float* __restrict__ Whh_f, const float* __restrict__ Whh_b,
                       const int* __restrict__ lens,
                       short* __restrict__ Gimg, short* __restrict__ Wimg,
                       int* __restrict__ cnt) {
    int blk = blockIdx.x;
    int tid = threadIdx.x;
    if (blk < NB_G) {
        int idx = blk * 256 + tid;
        if (idx >= 2 * GSH) return;
        int d = idx / GSH;
        int rem = idx % GSH;
        int v = rem / GSTR;
        int u = (rem % GSTR) >> 2;
        int g = idx & 3;
        if (u >= HH) { Gimg[idx] = 0; return; }
        int r = g * HH + u;
        const float* Wih = d ? Wih_b : Wih_f;
        const float* bih = d ? bih_b : bih_f;
        const float* bhh = d ? bhh_b : bhh_f;
        float s = bih[r] + bhh[r];
        if (v != 0) {  // PAD row of emb is zero
            #pragma unroll 10
            for (int e = 0; e < HH; ++e) s = fmaf(emb[v * HH + e], Wih[r * HH + e], s);
        }
        Gimg[idx] = f2bf(s);
    } else if (blk < NB_G + NB_W) {
        int idx = (blk - NB_G) * 256 + tid;
        if (idx >= 2 * WSH) return;
        int d = idx / WSH;
        int e = idx % WSH;
        int t = e >> 10, m = (e >> 6) & 15, k = e & 63;
        int u = 4 * t + (m >> 2), g = m & 3;
        const float* Whh = d ? Whh_b : Whh_f;
        float val = (k < HH && u < HH) ? Whh[(g * HH + u) * HH + k] : 0.0f;
        int ksw = (k & 7) | (((k >> 3) ^ (m & 7)) << 3);
        Wimg[d * WSH + (e & ~63) + ksw] = f2bf(val);
    } else {
        int hb = blk - NB_G - NB_W;      // 0..127
        __shared__ int hcnt[21];
        if (tid < 21) hcnt[tid] = 0;
        __syncthreads();
        atomicAdd(&hcnt[lens[hb * 256 + tid]], 1);
        __syncthreads();
        if (tid < 21) cnt[hb * 21 + tid] = hcnt[tid];
    }
}

// offs[b][L] = start of (bucket L, block b) region; buckets ordered L=20..0.
__global__ void k_scan(const int* __restrict__ cnt, int* __restrict__ offs) {
    __shared__ int tot[21], start[21];
    int t = threadIdx.x;
    if (t < 21) {
        int s = 0;
        for (int b = 0; b < NB_H; ++b) s += cnt[b * 21 + t];
        tot[t] = s;
    }
    __syncthreads();
    if (t == 0) {
        int acc = 0;
        for (int L = 20; L >= 0; --L) { start[L] = acc; acc += tot[L]; }
    }
    __syncthreads();
    if (t < 21) {
        int acc = start[t];
        for (int b = 0; b < NB_H; ++b) { offs[b * 21 + t] = acc; acc += cnt[b * 21 + t]; }
    }
}

__global__ void k_scat(const int* __restrict__ lens, const int* __restrict__ offs,
                       int* __restrict__ perm) {
    __shared__ int cur[21];
    int b = blockIdx.x, t = threadIdx.x;
    if (t < 21) cur[t] = offs[b * 21 + t];
    __syncthreads();
    int i = b * 256 + t;
    int pos = atomicAdd(&cur[lens[i]], 1);
    perm[pos] = i;
}

__launch_bounds__(512, 1)
__global__ void k_lstm(const int* __restrict__ chars, const int* __restrict__ lens,
                       const int* __restrict__ perm,
                       const short* __restrict__ Gimg, const short* __restrict__ Wimg,
                       float* __restrict__ out) {
    __shared__ __align__(16) short Wa[WSH];        // 26624 B
    __shared__ __align__(16) short Gl[GSH];        // 84800 B
    __shared__ __align__(16) short hs[8][1024];    // per-wave h (bf16, swizzled)
    __shared__ unsigned char cs[8][320];           // per-wave chars (u8)

    int gb   = blockIdx.x;         // 0..511
    int d    = gb & 1;             // interleave dirs so long blocks dispatch first
    int grp  = gb >> 1;            // 0..255
    int tid  = threadIdx.x;        // 0..511
    int lane = tid & 63;
    int wv   = __builtin_amdgcn_readfirstlane(tid >> 6);   // 0..7
    int quad = lane >> 4;
    int n    = lane & 15;
    int x7   = n & 7;

    // ---- stage: coalesced block copies ----
    {
        const int4* src = (const int4*)(Wimg + d * WSH);
        int4* dst = (int4*)Wa;
        for (int i = tid; i < WSH / 8; i += 512) dst[i] = src[i];
    }
    {
        const int4* src = (const int4*)(Gimg + d * GSH);
        int4* dst = (int4*)Gl;
        for (int i = tid; i < GSH / 8; i += 512) dst[i] = src[i];
    }
    {
        int4 z = {0, 0, 0, 0};
        int4* hz = (int4*)&hs[0][0];
        for (int i = tid; i < 8 * 1024 / 8; i += 512) hz[i] = z;
    }
    int slotbase = (grp * 8 + wv) * 16;        // wave's first sorted slot
    {   // wave's 16 words x 20 chars -> u8 LDS (words scattered via perm)
        for (int i = lane; i < 16 * TT; i += 64) {
            int w = perm[slotbase + i / TT];
            cs[wv][i] = (unsigned char)chars[w * TT + i % TT];
        }
    }
    __syncthreads();

    int word = perm[slotbase + n];
    int L = lens[word];
    int mL = L;
    #pragma unroll
    for (int off = 8; off; off >>= 1) {
        int t2 = __shfl_xor(mL, off);
        mL = mL > t2 ? mL : t2;
    }
    mL = __builtin_amdgcn_readfirstlane(mL);

    const bf16x8* ap = (const bf16x8*)Wa;
    const bf16x8* bp = (const bf16x8*)hs[wv];
    short* hw = hs[wv];
    const unsigned char* cw = cs[wv] + n * TT;

    int pa0 = quad ^ x7;           // swizzled k-group, k 0..31
    int pa1 = (quad + 4) ^ x7;     // k 32..63

    float cst[TILES], hf[TILES];
    #pragma unroll
    for (int t = 0; t < TILES; ++t) { cst[t] = 0.0f; hf[t] = 0.0f; }

    #pragma unroll 1
    for (int s = 0; s < mL; ++s) {
        bool valid = s < L;
        int p = valid ? (d ? (L - 1 - s) : s) : 0;
        int v = cw[p];

        bf16x8 B0 = bp[n * 8 + pa0];     // h of step s-1, B-operand layout
        bf16x8 B1 = bp[n * 8 + pa1];

        // pass 1: MFMAs; acc init = bf16 G from LDS (char preactivation)
        f32x4 acc[TILES];
        #pragma unroll
        for (int t = 0; t < TILES; ++t) {
            int u = 4 * t + quad;
            s16x4 gv = *(const s16x4*)&Gl[v * GSTR + u * 4];
            f32x4 a;
            a[0] = bf2f(gv[0]); a[1] = bf2f(gv[1]);
            a[2] = bf2f(gv[2]); a[3] = bf2f(gv[3]);
            bf16x8 A0 = ap[(t * 16 + n) * 8 + pa0];
            bf16x8 A1 = ap[(t * 16 + n) * 8 + pa1];
            a = __builtin_amdgcn_mfma_f32_16x16x32_bf16(A0, B0, a, 0, 0, 0);
            a = __builtin_amdgcn_mfma_f32_16x16x32_bf16(A1, B1, a, 0, 0, 0);
            acc[t] = a;
        }
        // pass 2: lane-local gate math; h back to LDS in bf16
        #pragma unroll
        for (int t = 0; t < TILES; ++t) {
            int u = 4 * t + quad;
            float ig = fsig(acc[t][0]);
            float fg = fsig(acc[t][1]);
            float gg = ftanhf(acc[t][2]);
            float og = fsig(acc[t][3]);
            float cold = cst[t];
            float cn = fg * cold + ig * gg;
            float hn = og * ftanhf(cn);
            bool upd = valid && (u < HH);
            cst[t] = upd ? cn : cold;
            hf[t]  = upd ? hn : hf[t];
            if (upd) {
                int idx = n * 64 + (((u >> 3) ^ x7) << 3) + (u & 7);
                hw[idx] = f2bf(hn);      // skipped when invalid -> h frozen
            }
        }
    }

    float* orow = out + (size_t)word * (2 * HH) + d * HH;
    #pragma unroll
    for (int t = 0; t < TILES; ++t) {
        int u = 4 * t + quad;
        if (u < HH) orow[u] = hf[t];     // fp32 h
    }
}

extern "C" void kernel_launch(void* const* d_in, const int* in_sizes, int n_in,
                              void* d_out, int out_size, void* d_ws, size_t ws_size,
                              hipStream_t stream) {
    const int*   chars = (const int*)d_in[0];
    const int*   lens  = (const int*)d_in[1];
    const float* emb   = (const float*)d_in[2];
    const float* Wih_f = (const float*)d_in[3];
    const float* Whh_f = (const float*)d_in[4];
    const float* bih_f = (const float*)d_in[5];
    const float* bhh_f = (const float*)d_in[6];
    const float* Wih_b = (const float*)d_in[7];
    const float* Whh_b = (const float*)d_in[8];
    const float* bih_b = (const float*)d_in[9];
    const float* bhh_b = (const float*)d_in[10];
    float* out = (float*)d_out;

    short* Gimg = (short*)d_ws;                 // 169600 B
    short* Wimg = Gimg + 2 * GSH;               //  53248 B
    int*   cnt  = (int*)(Wimg + 2 * WSH);       //  10752 B
    int*   offs = cnt + NB_H * 21;              //  10752 B
    int*   perm = offs + NB_H * 21;             // 131072 B   (total ~375 KB)

    k_prep<<<NB_G + NB_W + NB_H, 256, 0, stream>>>(emb, Wih_f, bih_f, bhh_f,
                                                   Wih_b, bih_b, bhh_b,
                                                   Whh_f, Whh_b, lens,
                                                   Gimg, Wimg, cnt);
    k_scan<<<1, 64, 0, stream>>>(cnt, offs);
    k_scat<<<NB_H, 256, 0, stream>>>(lens, offs, perm);
    k_lstm<<<512, 512, 0, stream>>>(chars, lens, perm, Gimg, Wimg, out);
}